// Round 1
// baseline (372.156 us; speedup 1.0000x reference)
//
#include <hip/hip_runtime.h>
#include <math.h>

// Problem constants
#define HD    64     // hidden
#define NIN   1535   // input nodes
#define NN    1536   // total nodes (input + 1 output node)
#define BB    32     // batch
#define BN_EPS 1e-5f

// Workspace layout (in floats):
//  [0,64)              u        = WK^T @ wQKk   (so sk = h·u + c)
//  [64]                c        = bK·wQKk
//  [128, 128+4096)     WAV      = WA @ WV       (folded round matrix)
//  [4224, 4224+64)     bAV      = bA + WA @ bV
//  [8192, 8192+49152)  skbuf    [B][NN] scores
//  [57344, 57344+2048) zbuf     [B][H] round-1 pre-BN output
//  [65536, +3145728)   hbuf     [B][NN][H] encoded node features
// Total = 3,211,264 floats = 12.25 MiB of d_ws.
#define WS_U     0
#define WS_C     64
#define WS_WAV   128
#define WS_BAV   4224
#define WS_SK    8192
#define WS_Z     57344
#define WS_H     65536

// ---------------------------------------------------------------- kernel 0
// Fold weights: u, c, WAV = WA@WV, bAV = bA + WA@bV. One block.
__global__ __launch_bounds__(256) void k_prep(
    const float* __restrict__ WK, const float* __restrict__ bK,
    const float* __restrict__ wQKk,
    const float* __restrict__ WV, const float* __restrict__ bV,
    const float* __restrict__ WA, const float* __restrict__ bA,
    float* __restrict__ ws) {
  int t = threadIdx.x;
  float* u   = ws + WS_U;
  float* cC  = ws + WS_C;
  float* WAV = ws + WS_WAV;
  float* bAV = ws + WS_BAV;
  // WAV[i][j] = sum_k WA[i][k] * WV[k][j]
  for (int e = t; e < HD * HD; e += 256) {
    int i = e >> 6, j = e & 63;
    float a = 0.f;
    for (int k = 0; k < HD; k++) a += WA[i * HD + k] * WV[k * HD + j];
    WAV[e] = a;
  }
  if (t < HD) {
    float a = 0.f;
    for (int h = 0; h < HD; h++) a += wQKk[h] * WK[h * HD + t];
    u[t] = a;
    float ab = bA[t];
    for (int k = 0; k < HD; k++) ab += WA[t * HD + k] * bV[k];
    bAV[t] = ab;
  }
  if (t == 0) {
    float cc = 0.f;
    for (int h = 0; h < HD; h++) cc += wQKk[h] * bK[h];
    cC[0] = cc;
  }
}

// ---------------------------------------------------------------- kernel 1
// Encode every (batch,node) row -> h [B][NN][H], and per-row score
// sk = h·u + c via wave reduction. One wave per row, 4 rows per block.
__global__ __launch_bounds__(256) void k_encode(
    const float* __restrict__ xx,   // [B,NIN,8]
    const float* __restrict__ yy,   // [B,NIN]
    const float* __restrict__ oxx,  // [B,1,8]
    const float* __restrict__ W1, const float* __restrict__ b1,   // [H,9],[H]
    const float* __restrict__ W2, const float* __restrict__ b2,   // [H,H],[H]
    const float* __restrict__ Wenc, const float* __restrict__ benc, // [H,8],[H]
    float* __restrict__ ws) {
  const float* u  = ws + WS_U;
  const float* cC = ws + WS_C;
  float* skb  = ws + WS_SK;
  float* hbuf = ws + WS_H;

  int w = threadIdx.x >> 6;        // wave id in block (0..3)
  int lane = threadIdx.x & 63;
  int r = blockIdx.x * 4 + w;      // row = b*NN + i
  int b = r / NN;
  int i = r - b * NN;

  __shared__ float sh1[4][HD];

  float val;
  if (i < NIN) {
    const float* xp = xx + ((size_t)b * NIN + i) * 8;
    float x8 = yy[(size_t)b * NIN + i];
    const float* wr = W1 + lane * 9;
    float a = b1[lane];
    a += xp[0]*wr[0] + xp[1]*wr[1] + xp[2]*wr[2] + xp[3]*wr[3];
    a += xp[4]*wr[4] + xp[5]*wr[5] + xp[6]*wr[6] + xp[7]*wr[7];
    a += x8 * wr[8];
    val = fmaxf(a, 0.f);
  } else {
    const float* xp = oxx + b * 8;
    const float* wr = Wenc + lane * 8;
    float a = benc[lane];
    #pragma unroll
    for (int k = 0; k < 8; k++) a += xp[k] * wr[k];
    val = fmaxf(a, 0.f);
  }
  sh1[w][lane] = val;
  __syncthreads();

  float h2;
  if (i < NIN) {
    const float* wr = W2 + lane * HD;
    float a = b2[lane];
    #pragma unroll
    for (int k = 0; k < HD; k++) a += sh1[w][k] * wr[k];
    h2 = fmaxf(a, 0.f);
  } else {
    h2 = val;  // output-node encoder is single-layer
  }
  hbuf[(size_t)r * HD + lane] = h2;

  // score: sk[r] = h2·u + c (wave reduce over 64 lanes)
  float p = h2 * u[lane];
  for (int off = 32; off > 0; off >>= 1) p += __shfl_down(p, off, 64);
  if (lane == 0) skb[r] = p + cC[0];
}

// ---------------------------------------------------------------- kernel 2
// Per batch b: softmax over NN scores, weighted node-feature average s,
// then z = s @ WAV^T + bAV  (round-1 pre-BN output). One block per batch.
__global__ __launch_bounds__(256) void k_attn(float* __restrict__ ws) {
  const float* WAV = ws + WS_WAV;
  const float* bAV = ws + WS_BAV;
  const float* skb = ws + WS_SK;
  const float* hbuf = ws + WS_H;
  float* zbuf = ws + WS_Z;

  int b = blockIdx.x, t = threadIdx.x;
  __shared__ float e_s[NN];
  __shared__ float rbuf[256];
  __shared__ float ss[HD];

  // 1. load scores, block max
  float m = -1e30f;
  for (int j = t; j < NN; j += 256) {
    float v = skb[b * NN + j];
    e_s[j] = v;
    m = fmaxf(m, v);
  }
  rbuf[t] = m;
  __syncthreads();
  for (int s = 128; s > 0; s >>= 1) {
    if (t < s) rbuf[t] = fmaxf(rbuf[t], rbuf[t + s]);
    __syncthreads();
  }
  float M = rbuf[0];
  __syncthreads();

  // 2. exp + block sum
  float sum = 0.f;
  for (int j = t; j < NN; j += 256) {
    float e = expf(e_s[j] - M);
    e_s[j] = e;
    sum += e;
  }
  rbuf[t] = sum;
  __syncthreads();
  for (int s = 128; s > 0; s >>= 1) {
    if (t < s) rbuf[t] += rbuf[t + s];
    __syncthreads();
  }
  float S = rbuf[0];
  __syncthreads();

  // 3. weighted feature sum: s[h] = sum_j e_j * h[b][j][h] / S
  int h = t & 63, g = t >> 6;
  float acc = 0.f;
  const float* hb = hbuf + (size_t)b * NN * HD;
  for (int j = g; j < NN; j += 4) acc += e_s[j] * hb[(size_t)j * HD + h];
  rbuf[t] = acc;
  __syncthreads();
  if (t < HD) {
    float s4 = rbuf[t] + rbuf[64 + t] + rbuf[128 + t] + rbuf[192 + t];
    ss[t] = s4 / S;
  }
  __syncthreads();

  // 4. z = ss @ WAV^T + bAV
  if (t < HD) {
    const float* wr = WAV + t * HD;
    float a = bAV[t];
    #pragma unroll 8
    for (int k = 0; k < HD; k++) a += ss[k] * wr[k];
    zbuf[b * HD + t] = a;
  }
}

// ---------------------------------------------------------------- kernel 3
// BN(round1) + rounds 2..4 (matvec with folded WAV + BN + relu) + heads.
// Entire remaining state is [B=32, H=64] -> one block.
__global__ __launch_bounds__(256) void k_tail(
    const float* __restrict__ ws,
    const float* __restrict__ gamma, const float* __restrict__ beta,
    const float* __restrict__ Wmu, const float* __restrict__ bmu,
    const float* __restrict__ Wsig, const float* __restrict__ bsig,
    float* __restrict__ out) {
  const float* WAV = ws + WS_WAV;
  const float* bAV = ws + WS_BAV;
  const float* zb  = ws + WS_Z;

  __shared__ float n_s[BB * HD];
  __shared__ float z_s[BB * HD];
  __shared__ float sc_s[HD], sh_s[HD];
  int t = threadIdx.x;

  for (int e = t; e < BB * HD; e += 256) z_s[e] = zb[e];
  __syncthreads();

  for (int round = 0; round < 4; round++) {
    // BatchNorm over batch axis per feature (two-pass mean/var, ddof=0)
    if (t < HD) {
      float s1 = 0.f;
      for (int bb = 0; bb < BB; bb++) s1 += z_s[bb * HD + t];
      float mu = s1 * (1.0f / BB);
      float s2 = 0.f;
      for (int bb = 0; bb < BB; bb++) {
        float d = z_s[bb * HD + t] - mu;
        s2 += d * d;
      }
      float var = s2 * (1.0f / BB);
      float inv = gamma[t] / sqrtf(var + BN_EPS);
      sc_s[t] = inv;
      sh_s[t] = beta[t] - mu * inv;
    }
    __syncthreads();
    for (int e = t; e < BB * HD; e += 256) {
      int hh = e & 63;
      n_s[e] = fmaxf(z_s[e] * sc_s[hh] + sh_s[hh], 0.f);
    }
    __syncthreads();
    if (round < 3) {
      // nodes all identical -> uniform softmax -> aggre = v = n@WV^T+bV,
      // z = aggre@WA^T+bA = n@WAV^T + bAV (folded)
      for (int e = t; e < BB * HD; e += 256) {
        int hh = e & 63;
        const float* nr = n_s + (e >> 6) * HD;
        const float* wr = WAV + hh * HD;
        float a = bAV[hh];
        #pragma unroll 8
        for (int k = 0; k < HD; k++) a += nr[k] * wr[k];
        z_s[e] = a;
      }
      __syncthreads();
    }
  }

  // heads: agg = max over identical nodes = n4
  if (t < BB) {
    const float* nr = n_s + t * HD;
    float m = bmu[0], sg = bsig[0];
    #pragma unroll 8
    for (int h = 0; h < HD; h++) {
      float v = nr[h];
      m += v * Wmu[h];
      sg += v * Wsig[h];
    }
    out[t] = m;                       // mu_out [B,1] flat
    out[BB + t] = sg * sg + 0.01f;    // sig_out [B,1] flat
  }
}

// ---------------------------------------------------------------- launch
extern "C" void kernel_launch(void* const* d_in, const int* in_sizes, int n_in,
                              void* d_out, int out_size, void* d_ws, size_t ws_size,
                              hipStream_t stream) {
  const float* xx   = (const float*)d_in[0];   // input_xx [B,N,8]
  const float* yy   = (const float*)d_in[1];   // input_yy [B,N]
  const float* oxx  = (const float*)d_in[2];   // output_xx [B,1,8]
  const float* W1   = (const float*)d_in[3];
  const float* b1   = (const float*)d_in[4];
  const float* W2   = (const float*)d_in[5];
  const float* b2   = (const float*)d_in[6];
  const float* Wenc = (const float*)d_in[7];
  const float* benc = (const float*)d_in[8];
  // d_in[9]=WQ, d_in[10]=bQ, d_in[15]=wQKq, d_in[17]=bQK: provably unused
  // (the i-dependent score term is constant over the softmax axis).
  const float* WK   = (const float*)d_in[11];
  const float* bK   = (const float*)d_in[12];
  const float* WV   = (const float*)d_in[13];
  const float* bV   = (const float*)d_in[14];
  const float* wQKk = (const float*)d_in[16];
  const float* WA   = (const float*)d_in[18];
  const float* bA   = (const float*)d_in[19];
  const float* gamma= (const float*)d_in[20];
  const float* beta = (const float*)d_in[21];
  const float* Wmu  = (const float*)d_in[22];
  const float* bmu  = (const float*)d_in[23];
  const float* Wsig = (const float*)d_in[24];
  const float* bsig = (const float*)d_in[25];

  float* ws  = (float*)d_ws;
  float* out = (float*)d_out;

  k_prep<<<1, 256, 0, stream>>>(WK, bK, wQKk, WV, bV, WA, bA, ws);
  k_encode<<<(BB * NN) / 4, 256, 0, stream>>>(xx, yy, oxx, W1, b1, W2, b2,
                                              Wenc, benc, ws);
  k_attn<<<BB, 256, 0, stream>>>(ws);
  k_tail<<<1, 256, 0, stream>>>(ws, gamma, beta, Wmu, bmu, Wsig, bsig, out);
}

// Round 2
// 148.208 us; speedup vs baseline: 2.5110x; 2.5110x over previous
//
#include <hip/hip_runtime.h>
#include <math.h>

// Problem constants
#define HD    64     // hidden
#define NIN   1535   // input nodes
#define NN    1536   // total nodes
#define BB    32     // batch
#define BN_EPS 1e-5f
#define CH    64     // rows per chunk
#define NCH   24     // chunks per batch (24*64 = 1536)

// Workspace layout (floats):
//   M_ws [768], S_ws [768], vec_ws [768][64]
#define WS_M  0
#define WS_S  768
#define WS_V  1536

// ================================================================ k_main
// Per block: batch b, chunk c (64 rows). Encode rows (fc1+relu, fc2+relu;
// output node uses enc path), compute per-row attention score sk = h2·u
// (the i-dependent score term is constant over the softmax axis and the
// bK·wQKk constant cancels in softmax -> both dropped), and emit a
// flash-style partial (m, sum_e, sum_e*h) for this chunk.
__global__ __launch_bounds__(256) void k_main(
    const float* __restrict__ xx,   // [B,NIN,8]
    const float* __restrict__ yy,   // [B,NIN]
    const float* __restrict__ oxx,  // [B,1,8]
    const float* __restrict__ W1, const float* __restrict__ b1,
    const float* __restrict__ W2, const float* __restrict__ b2,
    const float* __restrict__ Wenc, const float* __restrict__ benc,
    const float* __restrict__ WK, const float* __restrict__ wQKk,
    float* __restrict__ ws) {
  __shared__ float W1s[576];          // [64][9] stride 9 (odd -> 2-way, free)
  __shared__ float b1s[64], b2s[64], bencs[64], us[64];
  __shared__ float Wencs[512];        // [64][8]
  __shared__ float W2Ts[64 * 65];     // W2T[k][h] at k*65+h (pad -> no conflicts)
  __shared__ float xs[512];           // [64 rows][8]
  __shared__ float ys[64];
  __shared__ float h1s[4][64];        // per-wave fc1 output
  __shared__ float h2s[64 * 64];      // chunk node features
  __shared__ float sks[64], e_s[64], rbuf[256], red0[1];

  const int t = threadIdx.x;
  const int blk = blockIdx.x;
  const int b = blk & 31;
  const int c = blk >> 5;
  const int pp = b * NCH + c;        // partial index

  // ---- stage weights + inputs (coalesced) ----
  for (int e = t; e < 576; e += 256) W1s[e] = W1[e];
  for (int e = t; e < 512; e += 256) Wencs[e] = Wenc[e];
  for (int e = t; e < 4096; e += 256) {
    int h = e >> 6, k = e & 63;
    W2Ts[k * 65 + h] = W2[e];
  }
  for (int e = t; e < 512; e += 256) {
    int j = e >> 3, k = e & 7;
    int r0 = c * CH + j;
    xs[e] = (r0 < NIN) ? xx[(size_t)b * (NIN * 8) + (size_t)r0 * 8 + k]
                       : oxx[b * 8 + k];
  }
  if (t < 64) {
    b1s[t] = b1[t]; b2s[t] = b2[t]; bencs[t] = benc[t];
    int r0 = c * CH + t;
    ys[t] = (r0 < NIN) ? yy[b * NIN + r0] : 0.f;
    // u = WK^T @ wQKk (coalesced per iter; fully unrolled -> loads pipeline)
    float a = 0.f;
    #pragma unroll
    for (int h0 = 0; h0 < 64; h0++) a += wQKk[h0] * WK[h0 * 64 + t];
    us[t] = a;
  }
  __syncthreads();

  const int w = t >> 6, lane = t & 63;
  float* h1w = h1s[w];

  // each lane caches its W2 column (W2[lane][k], k=0..63) in VGPRs once
  float w2r[64];
  #pragma unroll
  for (int k = 0; k < 64; k++) w2r[k] = W2Ts[k * 65 + lane];

  // ---- 16 rows per wave ----
  for (int rr = 0; rr < 16; rr++) {
    int j = w * 16 + rr;
    int r0 = c * CH + j;
    const float* xr = xs + j * 8;
    float h2;
    if (r0 < NIN) {                       // wave-uniform branch
      const float* wr = W1s + lane * 9;
      float a = b1s[lane];
      a += xr[0] * wr[0] + xr[1] * wr[1] + xr[2] * wr[2] + xr[3] * wr[3];
      a += xr[4] * wr[4] + xr[5] * wr[5] + xr[6] * wr[6] + xr[7] * wr[7];
      a += ys[j] * wr[8];
      h1w[lane] = fmaxf(a, 0.f);          // wave-synchronous LDS
      float a0 = b2s[lane], a1 = 0.f;
      #pragma unroll
      for (int k = 0; k < 64; k += 4) {
        float4 hv = *(const float4*)(h1w + k);   // broadcast b128
        a0 += hv.x * w2r[k]     + hv.z * w2r[k + 2];
        a1 += hv.y * w2r[k + 1] + hv.w * w2r[k + 3];
      }
      h2 = fmaxf(a0 + a1, 0.f);
    } else {                              // output node: single enc layer
      const float* wr = Wencs + lane * 8;
      float a = bencs[lane];
      #pragma unroll
      for (int k = 0; k < 8; k++) a += xr[k] * wr[k];
      h2 = fmaxf(a, 0.f);
    }
    h2s[j * 64 + lane] = h2;
    // score = h2 . u  (wave reduce)
    float p = h2 * us[lane];
    p += __shfl_down(p, 32); p += __shfl_down(p, 16); p += __shfl_down(p, 8);
    p += __shfl_down(p, 4);  p += __shfl_down(p, 2);  p += __shfl_down(p, 1);
    if (lane == 0) sks[j] = p;
  }
  __syncthreads();

  // ---- chunk softmax partial ----
  if (t < 64) {
    float m = sks[t];
    m = fmaxf(m, __shfl_down(m, 32)); m = fmaxf(m, __shfl_down(m, 16));
    m = fmaxf(m, __shfl_down(m, 8));  m = fmaxf(m, __shfl_down(m, 4));
    m = fmaxf(m, __shfl_down(m, 2));  m = fmaxf(m, __shfl_down(m, 1));
    if (t == 0) red0[0] = m;
  }
  __syncthreads();
  float M = red0[0];
  if (t < 64) {
    float e = expf(sks[t] - M);
    e_s[t] = e;
    float s = e;
    s += __shfl_down(s, 32); s += __shfl_down(s, 16); s += __shfl_down(s, 8);
    s += __shfl_down(s, 4);  s += __shfl_down(s, 2);  s += __shfl_down(s, 1);
    if (t == 0) { ws[WS_M + pp] = M; ws[WS_S + pp] = s; }
  }
  __syncthreads();
  // vec = sum_j e_j * h2[j][:]
  {
    float acc = 0.f;
    for (int j = w; j < 64; j += 4) acc += e_s[j] * h2s[j * 64 + lane];
    rbuf[t] = acc;
    __syncthreads();
    if (t < 64)
      ws[WS_V + pp * 64 + t] =
          rbuf[t] + rbuf[64 + t] + rbuf[128 + t] + rbuf[192 + t];
  }
}

// ================================================================ k_tail
// One block: fold WAV = WA@WV (in LDS), combine softmax partials, round-1
// z = ss@WAV^T + bAV, then rounds 2..4 on identical nodes (uniform softmax
// = identity) + BN + relu, then heads.
__global__ __launch_bounds__(256) void k_tail(
    const float* __restrict__ ws,
    const float* __restrict__ WV, const float* __restrict__ bV,
    const float* __restrict__ WA, const float* __restrict__ bA,
    const float* __restrict__ gamma, const float* __restrict__ beta,
    const float* __restrict__ Wmu, const float* __restrict__ bmu,
    const float* __restrict__ Wsig, const float* __restrict__ bsig,
    float* __restrict__ out) {
  __shared__ float WAs[64 * 65];   // WA[h][m] at h*65+m
  __shared__ float WVs[4096];      // WV[m][k]
  __shared__ float WAVT[4096];     // WAVT[k][h] = (WA@WV)[h][k]
  __shared__ float bAVs[64];
  __shared__ float Ml[768], Sl[768], wexp[768];
  __shared__ float Mb[32], iSb[32];
  __shared__ float st[32 * 66];    // stride 66: bank = (2b+k)%32, conflict-free
  __shared__ float zs[32 * 66];
  __shared__ float scs[64], shs[64];
  const int t = threadIdx.x;

  for (int e = t; e < 4096; e += 256) {
    int h = e >> 6, m = e & 63;
    WAs[h * 65 + m] = WA[e];
    WVs[e] = WV[e];
  }
  for (int p = t; p < 768; p += 256) {
    Ml[p] = ws[WS_M + p];
    Sl[p] = ws[WS_S + p];
  }
  __syncthreads();

  if (t < 64) {
    float a = bA[t];
    #pragma unroll
    for (int k = 0; k < 64; k++) a += WAs[t * 65 + k] * bV[k];
    bAVs[t] = a;
  }
  // WAVT[k][h]: thread (kg=t>>6, h=t&63) computes 16 k's with ILP-16 accs
  {
    int kg = t >> 6, h = t & 63;
    float acc[16];
    #pragma unroll
    for (int kk = 0; kk < 16; kk++) acc[kk] = 0.f;
    for (int m = 0; m < 64; m++) {
      float wa = WAs[h * 65 + m];
      const float4* wv = (const float4*)(WVs + m * 64 + kg * 16);
      float4 w0 = wv[0], w1 = wv[1], w2 = wv[2], w3 = wv[3];
      acc[0]  += wa * w0.x; acc[1]  += wa * w0.y; acc[2]  += wa * w0.z; acc[3]  += wa * w0.w;
      acc[4]  += wa * w1.x; acc[5]  += wa * w1.y; acc[6]  += wa * w1.z; acc[7]  += wa * w1.w;
      acc[8]  += wa * w2.x; acc[9]  += wa * w2.y; acc[10] += wa * w2.z; acc[11] += wa * w2.w;
      acc[12] += wa * w3.x; acc[13] += wa * w3.y; acc[14] += wa * w3.z; acc[15] += wa * w3.w;
    }
    #pragma unroll
    for (int kk = 0; kk < 16; kk++) WAVT[(kg * 16 + kk) * 64 + h] = acc[kk];
  }
  if (t < 32) {
    float m = -1e30f;
    for (int cc = 0; cc < NCH; cc++) m = fmaxf(m, Ml[t * NCH + cc]);
    Mb[t] = m;
  }
  __syncthreads();
  for (int p = t; p < 768; p += 256) {
    int bb = p / NCH;
    wexp[p] = expf(Ml[p] - Mb[bb]);
  }
  __syncthreads();
  if (t < 32) {
    float s = 0.f;
    for (int cc = 0; cc < NCH; cc++) {
      int p = t * NCH + cc;
      s += Sl[p] * wexp[p];
    }
    iSb[t] = 1.0f / s;
  }
  __syncthreads();
  // ss[b][h] = (sum_c wexp * vec_c[h]) / S_b  -> st
  {
    int bb = t >> 3, hg = t & 7;
    float acc[8];
    #pragma unroll
    for (int jj = 0; jj < 8; jj++) acc[jj] = 0.f;
    for (int cc = 0; cc < NCH; cc++) {
      int p = bb * NCH + cc;
      float wgt = wexp[p];
      const float* vp = ws + WS_V + p * 64 + hg;
      #pragma unroll
      for (int jj = 0; jj < 8; jj++) acc[jj] += wgt * vp[jj * 8];
    }
    float is = iSb[bb];
    #pragma unroll
    for (int jj = 0; jj < 8; jj++) st[bb * 66 + hg + 8 * jj] = acc[jj] * is;
  }
  __syncthreads();

  // ---- 4 rounds: z = st@WAV^T + bAV; BN over batch; relu ----
  for (int r = 0; r < 4; r++) {
    {
      int bb = t >> 3, hg = t & 7;
      float acc[8];
      #pragma unroll
      for (int jj = 0; jj < 8; jj++) acc[jj] = bAVs[hg + 8 * jj];
      for (int k = 0; k < 64; k++) {
        float v = st[bb * 66 + k];
        const float* wp = WAVT + k * 64 + hg;
        #pragma unroll
        for (int jj = 0; jj < 8; jj++) acc[jj] += v * wp[8 * jj];
      }
      #pragma unroll
      for (int jj = 0; jj < 8; jj++) zs[bb * 66 + hg + 8 * jj] = acc[jj];
    }
    __syncthreads();
    if (t < 64) {
      float s1 = 0.f;
      for (int bb2 = 0; bb2 < BB; bb2++) s1 += zs[bb2 * 66 + t];
      float mu = s1 * (1.0f / BB);
      float s2 = 0.f;
      for (int bb2 = 0; bb2 < BB; bb2++) {
        float d = zs[bb2 * 66 + t] - mu;
        s2 += d * d;
      }
      float inv = gamma[t] / sqrtf(s2 * (1.0f / BB) + BN_EPS);
      scs[t] = inv;
      shs[t] = beta[t] - mu * inv;
    }
    __syncthreads();
    for (int e = t; e < BB * 64; e += 256) {
      int bb2 = e >> 6, hh = e & 63;
      st[bb2 * 66 + hh] = fmaxf(zs[bb2 * 66 + hh] * scs[hh] + shs[hh], 0.f);
    }
    __syncthreads();
  }

  // heads (agg = max over identical nodes = state itself)
  if (t < BB) {
    const float* nr = st + t * 66;
    float m = bmu[0], sg = bsig[0];
    #pragma unroll 8
    for (int h = 0; h < 64; h++) {
      float v = nr[h];
      m += v * Wmu[h];
      sg += v * Wsig[h];
    }
    out[t] = m;
    out[BB + t] = sg * sg + 0.01f;
  }
}

// ================================================================ launch
extern "C" void kernel_launch(void* const* d_in, const int* in_sizes, int n_in,
                              void* d_out, int out_size, void* d_ws, size_t ws_size,
                              hipStream_t stream) {
  const float* xx   = (const float*)d_in[0];
  const float* yy   = (const float*)d_in[1];
  const float* oxx  = (const float*)d_in[2];
  const float* W1   = (const float*)d_in[3];
  const float* b1   = (const float*)d_in[4];
  const float* W2   = (const float*)d_in[5];
  const float* b2   = (const float*)d_in[6];
  const float* Wenc = (const float*)d_in[7];
  const float* benc = (const float*)d_in[8];
  // d_in[9]=WQ, [10]=bQ, [15]=wQKq, [17]=bQK: provably unused (the
  // i-dependent score term is constant over the softmax axis; bK·wQKk
  // cancels too, so d_in[12]=bK is also unused).
  const float* WK   = (const float*)d_in[11];
  const float* WV   = (const float*)d_in[13];
  const float* bV   = (const float*)d_in[14];
  const float* wQKk = (const float*)d_in[16];
  const float* WA   = (const float*)d_in[18];
  const float* bA   = (const float*)d_in[19];
  const float* gamma= (const float*)d_in[20];
  const float* beta = (const float*)d_in[21];
  const float* Wmu  = (const float*)d_in[22];
  const float* bmu  = (const float*)d_in[23];
  const float* Wsig = (const float*)d_in[24];
  const float* bsig = (const float*)d_in[25];

  float* ws  = (float*)d_ws;
  float* out = (float*)d_out;

  k_main<<<BB * NCH, 256, 0, stream>>>(xx, yy, oxx, W1, b1, W2, b2, Wenc, benc,
                                       WK, wQKk, ws);
  k_tail<<<1, 256, 0, stream>>>(ws, WV, bV, WA, bA, gamma, beta,
                                Wmu, bmu, Wsig, bsig, out);
}